// Round 3
// baseline (148.775 us; speedup 1.0000x reference)
//
#include <hip/hip_runtime.h>

typedef __attribute__((ext_vector_type(4))) int   i32x4;
typedef __attribute__((ext_vector_type(4))) float f32x4;

#define HDIM 16
#define MDIM 2048
#define NDIM 2048
#define KDIM 128

// Pack 4 int32 (each 0..126, high bytes zero) into one dword of 4 int8.
__device__ inline int pack4(i32x4 v) {
    return v.x | (v.y << 8) | (v.z << 16) | (v.w << 24);
}

// ---------------------------------------------------------------------------
// Fused batched i8 GEMM: C[h] = A[h] (MxK int32, vals 0..126) * B[h]^T,
// packing int32->int8 in-register (no pack round-trip through HBM).
// Block: 128x128 tile, 4 waves 2x2; wave = 64x64 via 4x4 fragments of
// v_mfma_i32_16x16x64_i8, K = 2 unrolled steps of 64.
// OPERANDS SWAPPED: acc[mi][ni] = mfma(bf[ni], af[mi], acc) computes the
// transposed fragment, so lane (fr=lane&15, kg=lane>>4) holds
// C[m = bm+wm+mi*16+fr][n = bn+wn+ni*16+kg*4 + r], r=0..3 -> consecutive n
// -> float4 output stores, float4 scale_B loads.
// Epilogue: c = clamp(rint(acc * ((sA[m]/sO[m]) * sB[n])), -127, 127),
// stored as float32 (harness reads output as float32).
// ---------------------------------------------------------------------------
__global__ __launch_bounds__(256)
void gemm_i8_fused(const int* __restrict__ A,
                   const int* __restrict__ B,
                   const float* __restrict__ sA,
                   const float* __restrict__ sB,
                   const float* __restrict__ sO,
                   float* __restrict__ out) {
    const int h  = blockIdx.z;
    const int bm = blockIdx.y * 128;
    const int bn = blockIdx.x * 128;
    const int tid  = threadIdx.x;
    const int wave = tid >> 6;
    const int lane = tid & 63;
    const int wm = (wave >> 1) * 64;   // wave row offset in block tile
    const int wn = (wave & 1) * 64;    // wave col offset
    const int fr = lane & 15;          // fragment row for A/B loads; out row m
    const int kg = lane >> 4;          // 0..3 k-group; out n-subchunk

    const int* Ah = A + (size_t)h * MDIM * KDIM;
    const int* Bh = B + (size_t)h * NDIM * KDIM;

    i32x4 acc[4][4];
#pragma unroll
    for (int mi = 0; mi < 4; ++mi)
#pragma unroll
        for (int ni = 0; ni < 4; ++ni)
            acc[mi][ni] = (i32x4){0, 0, 0, 0};

#pragma unroll
    for (int ks = 0; ks < 2; ++ks) {
        const int kb = ks * 64 + kg * 16;   // int32 element index of 16-elem chunk
        i32x4 af[4], bf[4];
#pragma unroll
        for (int mi = 0; mi < 4; ++mi) {
            const i32x4* p = reinterpret_cast<const i32x4*>(
                Ah + (size_t)(bm + wm + mi * 16 + fr) * KDIM + kb);
            i32x4 v0 = p[0], v1 = p[1], v2 = p[2], v3 = p[3];
            af[mi] = (i32x4){pack4(v0), pack4(v1), pack4(v2), pack4(v3)};
        }
#pragma unroll
        for (int ni = 0; ni < 4; ++ni) {
            const i32x4* p = reinterpret_cast<const i32x4*>(
                Bh + (size_t)(bn + wn + ni * 16 + fr) * KDIM + kb);
            i32x4 v0 = p[0], v1 = p[1], v2 = p[2], v3 = p[3];
            bf[ni] = (i32x4){pack4(v0), pack4(v1), pack4(v2), pack4(v3)};
        }
#pragma unroll
        for (int mi = 0; mi < 4; ++mi)
#pragma unroll
            for (int ni = 0; ni < 4; ++ni)
                acc[mi][ni] = __builtin_amdgcn_mfma_i32_16x16x64_i8(
                    bf[ni], af[mi], acc[mi][ni], 0, 0, 0);  // swapped -> C^T frag
    }

    // Epilogue. Swapped layout: lane holds row m = bm+wm+mi*16+fr,
    // cols n = bn+wn+ni*16+kg*4 .. +3 (regs r=0..3 are consecutive n).
    const float* sAh = sA + h * MDIM;
    const float* sBh = sB + h * NDIM;
    const float* sOh = sO + h * MDIM;

    float smv[4];
#pragma unroll
    for (int mi = 0; mi < 4; ++mi) {
        const int m = bm + wm + mi * 16 + fr;
        smv[mi] = sAh[m] / sOh[m];          // reference op order: sA/sO first
    }
    f32x4 sbv[4];
#pragma unroll
    for (int ni = 0; ni < 4; ++ni)
        sbv[ni] = *reinterpret_cast<const f32x4*>(sBh + bn + wn + ni * 16 + kg * 4);

#pragma unroll
    for (int mi = 0; mi < 4; ++mi) {
        const int m = bm + wm + mi * 16 + fr;
        float* orow = out + ((size_t)h * MDIM + m) * NDIM + bn + wn + kg * 4;
#pragma unroll
        for (int ni = 0; ni < 4; ++ni) {
            f32x4 o;
#pragma unroll
            for (int r = 0; r < 4; ++r) {
                float c = (float)acc[mi][ni][r] * (smv[mi] * sbv[ni][r]);
                float rv = rintf(c);                       // RNE == np.round
                o[r] = fminf(fmaxf(rv, -127.0f), 127.0f);
            }
            __builtin_nontemporal_store(o, reinterpret_cast<f32x4*>(orow + ni * 16));
        }
    }
}

// Output 1: scale_out passthrough as float32 (exact).
__global__ void tail_scale_out(const float* __restrict__ sO,
                               float* __restrict__ out, int n) {
    int i = blockIdx.x * blockDim.x + threadIdx.x;
    if (i < n) out[i] = sO[i];
}

extern "C" void kernel_launch(void* const* d_in, const int* in_sizes, int n_in,
                              void* d_out, int out_size, void* d_ws, size_t ws_size,
                              hipStream_t stream) {
    const int*   A  = (const int*)d_in[0];
    const int*   B  = (const int*)d_in[1];
    const float* sA = (const float*)d_in[2];
    const float* sB = (const float*)d_in[3];
    const float* sO = (const float*)d_in[4];
    float* out = (float*)d_out;

    dim3 grid(NDIM / 128, MDIM / 128, HDIM);
    gemm_i8_fused<<<grid, 256, 0, stream>>>(A, B, sA, sB, sO, out);

    const int nTail = HDIM * MDIM;           // 32,768
    tail_scale_out<<<nTail / 256, 256, 0, stream>>>(
        sO, out + (size_t)HDIM * MDIM * NDIM, nTail);
}

// Round 4
// 99.637 us; speedup vs baseline: 1.4932x; 1.4932x over previous
//
#include <hip/hip_runtime.h>

typedef __attribute__((ext_vector_type(4))) int   i32x4;
typedef __attribute__((ext_vector_type(4))) float f32x4;

#define HDIM 16
#define MDIM 2048
#define NDIM 2048
#define KDIM 128

// ---------------------------------------------------------------------------
// Pack int32 (values 0..126, high bytes zero) -> int8. Each thread: 16 elems,
// 4x 16B loads -> 1x 16B store.
// ---------------------------------------------------------------------------
__global__ void pack_i32_to_i8(const int* __restrict__ src,
                               unsigned char* __restrict__ dst,
                               int n_threads) {
    int t = blockIdx.x * blockDim.x + threadIdx.x;
    if (t >= n_threads) return;
    const i32x4* s = reinterpret_cast<const i32x4*>(src) + (size_t)t * 4;
    i32x4 v0 = s[0], v1 = s[1], v2 = s[2], v3 = s[3];
    i32x4 o;
    o.x = v0.x | (v0.y << 8) | (v0.z << 16) | (v0.w << 24);
    o.y = v1.x | (v1.y << 8) | (v1.z << 16) | (v1.w << 24);
    o.z = v2.x | (v2.y << 8) | (v2.z << 16) | (v2.w << 24);
    o.w = v3.x | (v3.y << 8) | (v3.z << 16) | (v3.w << 24);
    reinterpret_cast<i32x4*>(dst)[t] = o;
}

// ---------------------------------------------------------------------------
// Batched i8 GEMM on pre-packed int8: C[h] = A[h] (MxK) * B[h]^T.
// Block: 128x128 tile, 4 waves 2x2; wave = 64x64 via 4x4 fragments of
// v_mfma_i32_16x16x64_i8, K = 2 unrolled steps of 64. 16 B/lane per fragment.
// OPERANDS SWAPPED: acc[mi][ni] = mfma(bf[ni], af[mi], acc) -> transposed
// fragment: lane (fr=lane&15, kg=lane>>4) holds
// C[m = bm+wm+mi*16+fr][n = bn+wn+ni*16+kg*4 + r], r=0..3 consecutive n
// -> float4 coalesced stores (64 B aligned segments), float4 scale_B loads.
// Epilogue: c = clamp(rint(acc * ((sA[m]/sO[m]) * sB[n])), -127, 127),
// stored as float32 (harness reads output buffer as float32).
// ---------------------------------------------------------------------------
__global__ __launch_bounds__(256)
void gemm_i8_fused(const unsigned char* __restrict__ A8,
                   const unsigned char* __restrict__ B8,
                   const float* __restrict__ sA,
                   const float* __restrict__ sB,
                   const float* __restrict__ sO,
                   float* __restrict__ out) {
    const int h  = blockIdx.z;
    const int bm = blockIdx.y * 128;
    const int bn = blockIdx.x * 128;
    const int tid  = threadIdx.x;
    const int wave = tid >> 6;
    const int lane = tid & 63;
    const int wm = (wave >> 1) * 64;   // wave row offset in block tile
    const int wn = (wave & 1) * 64;    // wave col offset
    const int fr = lane & 15;          // fragment row for A/B loads; out row m
    const int kg = lane >> 4;          // 0..3 k-group; out n-subchunk

    const unsigned char* Ah = A8 + (size_t)h * MDIM * KDIM;
    const unsigned char* Bh = B8 + (size_t)h * NDIM * KDIM;

    i32x4 acc[4][4];
#pragma unroll
    for (int mi = 0; mi < 4; ++mi)
#pragma unroll
        for (int ni = 0; ni < 4; ++ni)
            acc[mi][ni] = (i32x4){0, 0, 0, 0};

#pragma unroll
    for (int ks = 0; ks < 2; ++ks) {
        const int kb = ks * 64 + kg * 16;   // byte offset of this lane's 16B chunk
        i32x4 af[4], bf[4];
#pragma unroll
        for (int mi = 0; mi < 4; ++mi)
            af[mi] = *reinterpret_cast<const i32x4*>(
                Ah + (size_t)(bm + wm + mi * 16 + fr) * KDIM + kb);
#pragma unroll
        for (int ni = 0; ni < 4; ++ni)
            bf[ni] = *reinterpret_cast<const i32x4*>(
                Bh + (size_t)(bn + wn + ni * 16 + fr) * KDIM + kb);
#pragma unroll
        for (int mi = 0; mi < 4; ++mi)
#pragma unroll
            for (int ni = 0; ni < 4; ++ni)
                acc[mi][ni] = __builtin_amdgcn_mfma_i32_16x16x64_i8(
                    bf[ni], af[mi], acc[mi][ni], 0, 0, 0);  // swapped -> C^T frag
    }

    // Epilogue. Swapped layout: lane holds row m = bm+wm+mi*16+fr,
    // cols n = bn+wn+ni*16+kg*4 .. +3 (regs r=0..3 are consecutive n).
    const float* sAh = sA + h * MDIM;
    const float* sBh = sB + h * NDIM;
    const float* sOh = sO + h * MDIM;

    float smv[4];
#pragma unroll
    for (int mi = 0; mi < 4; ++mi) {
        const int m = bm + wm + mi * 16 + fr;
        smv[mi] = sAh[m] / sOh[m];          // reference op order: sA/sO first
    }
    f32x4 sbv[4];
#pragma unroll
    for (int ni = 0; ni < 4; ++ni)
        sbv[ni] = *reinterpret_cast<const f32x4*>(sBh + bn + wn + ni * 16 + kg * 4);

#pragma unroll
    for (int mi = 0; mi < 4; ++mi) {
        const int m = bm + wm + mi * 16 + fr;
        float* orow = out + ((size_t)h * MDIM + m) * NDIM + bn + wn + kg * 4;
#pragma unroll
        for (int ni = 0; ni < 4; ++ni) {
            f32x4 o;
#pragma unroll
            for (int r = 0; r < 4; ++r) {
                float c = (float)acc[mi][ni][r] * (smv[mi] * sbv[ni][r]);
                float rv = rintf(c);                       // RNE == np.round
                o[r] = fminf(fmaxf(rv, -127.0f), 127.0f);
            }
            *reinterpret_cast<f32x4*>(orow + ni * 16) = o; // plain store (L2 combines)
        }
    }
}

// Output 1: scale_out passthrough as float32 (exact).
__global__ void tail_scale_out(const float* __restrict__ sO,
                               float* __restrict__ out, int n) {
    int i = blockIdx.x * blockDim.x + threadIdx.x;
    if (i < n) out[i] = sO[i];
}

extern "C" void kernel_launch(void* const* d_in, const int* in_sizes, int n_in,
                              void* d_out, int out_size, void* d_ws, size_t ws_size,
                              hipStream_t stream) {
    const int*   A  = (const int*)d_in[0];
    const int*   B  = (const int*)d_in[1];
    const float* sA = (const float*)d_in[2];
    const float* sB = (const float*)d_in[3];
    const float* sO = (const float*)d_in[4];
    float* out = (float*)d_out;

    unsigned char* A8 = (unsigned char*)d_ws;
    unsigned char* B8 = A8 + (size_t)HDIM * MDIM * KDIM;

    const int nA = HDIM * MDIM * KDIM;       // 4,194,304 elements
    const int packThreads = nA / 16;         // 262,144
    pack_i32_to_i8<<<packThreads / 256, 256, 0, stream>>>(A, A8, packThreads);
    pack_i32_to_i8<<<packThreads / 256, 256, 0, stream>>>(B, B8, packThreads);

    dim3 grid(NDIM / 128, MDIM / 128, HDIM);
    gemm_i8_fused<<<grid, 256, 0, stream>>>(A8, B8, sA, sB, sO, out);

    const int nTail = HDIM * MDIM;           // 32,768
    tail_scale_out<<<nTail / 256, 256, 0, stream>>>(
        sO, out + (size_t)HDIM * MDIM * NDIM, nTail);
}

// Round 5
// 86.167 us; speedup vs baseline: 1.7266x; 1.1563x over previous
//
#include <hip/hip_runtime.h>

typedef __attribute__((ext_vector_type(4))) int   i32x4;
typedef __attribute__((ext_vector_type(4))) float f32x4;

#define HDIM 16
#define MDIM 2048
#define NDIM 2048
#define KDIM 128

// ---------------------------------------------------------------------------
// Combined prep kernel:
//  - packs A (int32 0..126 -> int8) into A8, B into B8  (16 elems/thread)
//  - copies scale_out passthrough into the output tail (float32, exact)
// One launch instead of three.
// ---------------------------------------------------------------------------
__global__ __launch_bounds__(256)
void prep_pack_tail(const int* __restrict__ A,
                    const int* __restrict__ B,
                    const float* __restrict__ sO,
                    unsigned char* __restrict__ A8,
                    unsigned char* __restrict__ B8,
                    float* __restrict__ out_tail) {
    const int nPackA = HDIM * MDIM * KDIM / 16;   // 262,144 threads for A
    int t = blockIdx.x * blockDim.x + threadIdx.x;

    const int* src;
    unsigned char* dst;
    int idx;
    if (t < nPackA) { src = A; dst = A8; idx = t; }
    else            { src = B; dst = B8; idx = t - nPackA; }

    const i32x4* s = reinterpret_cast<const i32x4*>(src) + (size_t)idx * 4;
    i32x4 v0 = s[0], v1 = s[1], v2 = s[2], v3 = s[3];
    i32x4 o;
    o.x = v0.x | (v0.y << 8) | (v0.z << 16) | (v0.w << 24);
    o.y = v1.x | (v1.y << 8) | (v1.z << 16) | (v1.w << 24);
    o.z = v2.x | (v2.y << 8) | (v2.z << 16) | (v2.w << 24);
    o.w = v3.x | (v3.y << 8) | (v3.z << 16) | (v3.w << 24);
    reinterpret_cast<i32x4*>(dst)[idx] = o;

    if (t < HDIM * MDIM)                           // 32,768 tail floats
        out_tail[t] = sO[t];
}

// ---------------------------------------------------------------------------
// Batched i8 GEMM on pre-packed int8: C[h] = A[h] (MxK) * B[h]^T.
// 1D grid of 4096 blocks with chunked XCD swizzle: hardware dispatches
// blocks round-robin across the 8 XCDs (i % 8); we remap so XCD k owns
// work ids [512k, 512k+512) = h in {2k, 2k+1}, all (by, bx), bx fastest.
// Effect: each XCD's L2 assembles complete 8 KB output rows (its 16 bx
// blocks are co-resident) and streams a contiguous 33.6 MB output slab.
//
// Block: 128x128 tile, 4 waves 2x2; wave = 64x64 via 4x4 fragments of
// v_mfma_i32_16x16x64_i8, K = 2 unrolled steps of 64. 16 B/lane/fragment.
// Swapped operands: acc[mi][ni] = mfma(bf[ni], af[mi], acc) -> lane
// (fr=lane&15, kg=lane>>4) holds C[m=...+fr][n=...+kg*4+r], r consecutive
// -> float4 coalesced stores (full aligned 64 B lines per quarter-wave).
// Epilogue: c = clamp(rint(acc * ((sA[m]/sO[m]) * sB[n])), -127, 127),
// stored as float32 (harness reads output buffer as float32).
// ---------------------------------------------------------------------------
__global__ __launch_bounds__(256)
void gemm_i8_fused(const unsigned char* __restrict__ A8,
                   const unsigned char* __restrict__ B8,
                   const float* __restrict__ sA,
                   const float* __restrict__ sB,
                   const float* __restrict__ sO,
                   float* __restrict__ out) {
    // chunked XCD swizzle: nwg = 4096, 8 XCDs, 512 per chunk
    const int i = blockIdx.x;
    const int w = (i & 7) * 512 + (i >> 3);
    const int bx = w & 15;
    const int by = (w >> 4) & 15;
    const int h  = w >> 8;

    const int bm = by * 128;
    const int bn = bx * 128;
    const int tid  = threadIdx.x;
    const int wave = tid >> 6;
    const int lane = tid & 63;
    const int wm = (wave >> 1) * 64;   // wave row offset in block tile
    const int wn = (wave & 1) * 64;    // wave col offset
    const int fr = lane & 15;          // fragment row for loads; out row m
    const int kg = lane >> 4;          // 0..3 k-group; out n-subchunk

    const unsigned char* Ah = A8 + (size_t)h * MDIM * KDIM;
    const unsigned char* Bh = B8 + (size_t)h * NDIM * KDIM;

    i32x4 acc[4][4];
#pragma unroll
    for (int mi = 0; mi < 4; ++mi)
#pragma unroll
        for (int ni = 0; ni < 4; ++ni)
            acc[mi][ni] = (i32x4){0, 0, 0, 0};

#pragma unroll
    for (int ks = 0; ks < 2; ++ks) {
        const int kb = ks * 64 + kg * 16;   // byte offset of this lane's 16B chunk
        i32x4 af[4], bf[4];
#pragma unroll
        for (int mi = 0; mi < 4; ++mi)
            af[mi] = *reinterpret_cast<const i32x4*>(
                Ah + (size_t)(bm + wm + mi * 16 + fr) * KDIM + kb);
#pragma unroll
        for (int ni = 0; ni < 4; ++ni)
            bf[ni] = *reinterpret_cast<const i32x4*>(
                Bh + (size_t)(bn + wn + ni * 16 + fr) * KDIM + kb);
#pragma unroll
        for (int mi = 0; mi < 4; ++mi)
#pragma unroll
            for (int ni = 0; ni < 4; ++ni)
                acc[mi][ni] = __builtin_amdgcn_mfma_i32_16x16x64_i8(
                    bf[ni], af[mi], acc[mi][ni], 0, 0, 0);  // swapped -> C^T frag
    }

    // Epilogue. Lane holds row m = bm+wm+mi*16+fr,
    // cols n = bn+wn+ni*16+kg*4 .. +3 (regs r=0..3 consecutive n).
    const float* sAh = sA + h * MDIM;
    const float* sBh = sB + h * NDIM;
    const float* sOh = sO + h * MDIM;

    float smv[4];
#pragma unroll
    for (int mi = 0; mi < 4; ++mi) {
        const int m = bm + wm + mi * 16 + fr;
        smv[mi] = sAh[m] / sOh[m];          // reference op order: sA/sO first
    }
    f32x4 sbv[4];
#pragma unroll
    for (int ni = 0; ni < 4; ++ni)
        sbv[ni] = *reinterpret_cast<const f32x4*>(sBh + bn + wn + ni * 16 + kg * 4);

#pragma unroll
    for (int mi = 0; mi < 4; ++mi) {
        const int m = bm + wm + mi * 16 + fr;
        float* orow = out + ((size_t)h * MDIM + m) * NDIM + bn + wn + kg * 4;
#pragma unroll
        for (int ni = 0; ni < 4; ++ni) {
            f32x4 o;
#pragma unroll
            for (int r = 0; r < 4; ++r) {
                float c = (float)acc[mi][ni][r] * (smv[mi] * sbv[ni][r]);
                float rv = rintf(c);                       // RNE == np.round
                o[r] = fminf(fmaxf(rv, -127.0f), 127.0f);
            }
            *reinterpret_cast<f32x4*>(orow + ni * 16) = o;
        }
    }
}

extern "C" void kernel_launch(void* const* d_in, const int* in_sizes, int n_in,
                              void* d_out, int out_size, void* d_ws, size_t ws_size,
                              hipStream_t stream) {
    const int*   A  = (const int*)d_in[0];
    const int*   B  = (const int*)d_in[1];
    const float* sA = (const float*)d_in[2];
    const float* sB = (const float*)d_in[3];
    const float* sO = (const float*)d_in[4];
    float* out = (float*)d_out;

    unsigned char* A8 = (unsigned char*)d_ws;
    unsigned char* B8 = A8 + (size_t)HDIM * MDIM * KDIM;

    const int packThreads = 2 * HDIM * MDIM * KDIM / 16;   // 524,288
    prep_pack_tail<<<packThreads / 256, 256, 0, stream>>>(
        A, B, sO, A8, B8, out + (size_t)HDIM * MDIM * NDIM);

    gemm_i8_fused<<<4096, 256, 0, stream>>>(A8, B8, sA, sB, sO, out);
}